// Round 3
// baseline (639.242 us; speedup 1.0000x reference)
//
#include <hip/hip_runtime.h>
#include <hip/hip_bf16.h>
#include <stdint.h>

#define N_NODES 100000
#define N_EDGES 1600000
#define CH 128
#define N_REL 8
#define N_PAD 100096            // N_NODES rounded up to multiple of 128 (GEMM strip pad)
#define N_KEYS (N_NODES * N_REL)

#define NBKT 782                // N_PAD / 128 coarse buckets (= fused grid)
#define BKT_CAP 4096            // bucket capacity; mean 2048, sigma~45 -> 45-sigma margin
#define N_KEYS_PAD (NBKT * 1024)

using frag_ab = __attribute__((ext_vector_type(8))) short;  // 8 bf16
using frag_cd = __attribute__((ext_vector_type(4))) float;  // 4 fp32

__device__ __forceinline__ short f2bs(float f) {
    union { __hip_bfloat16 h; short s; } u;
    u.h = __float2bfloat16(f);
    return u.s;
}

__device__ __forceinline__ uint32_t pack2bf(float a, float b) {
    union { __hip_bfloat16 h; unsigned short s; } ua, ub;
    ua.h = __float2bfloat16(a); ub.h = __float2bfloat16(b);
    return (uint32_t)ua.s | ((uint32_t)ub.s << 16);
}

__device__ __forceinline__ float bf_lo(uint32_t u) { return __uint_as_float(u << 16); }
__device__ __forceinline__ float bf_hi(uint32_t u) { return __uint_as_float(u & 0xffff0000u); }

// ======================= TIER 1: coarse bucket + in-LDS binning =======================
// R3: replaces {count_key, scan1, scan2, scan3, permute_key} (2x 1.6M random
// device atomics over 800k keys + 3-kernel scan chain, ~300us of prologue)
// with one hot-counter bucket pass + one LDS-local binning pass.

// one packed entry per edge: src<<10 | (dst&127)<<3 | rel   (src<2^17 fits)
__global__ void bucket_scatter(const int* __restrict__ ei, const int* __restrict__ et,
                               int* __restrict__ cur, uint32_t* __restrict__ bucket) {
    int e = blockIdx.x * 256 + threadIdx.x;
    if (e < N_EDGES) {
        int dst = ei[N_EDGES + e];
        int src = ei[e];
        int r = et[e];
        int b = dst >> 7;
        int pos = atomicAdd(&cur[b], 1);
        if (pos < BKT_CAP)
            bucket[(size_t)b * BKT_CAP + pos] =
                ((uint32_t)src << 10) | ((uint32_t)(dst & 127) << 3) | (uint32_t)r;
    }
}

// per bucket: LDS histogram over 1024 local keys, LDS scan, LDS-cursor scatter.
// writes sorted perm (src ids) into the bucket's fixed region [b*CAP, b*CAP+n)
// and absolute segment ENDS for the 1024 local keys.
__global__ __launch_bounds__(512)
void bin_kernel(const int* __restrict__ cur, const uint32_t* __restrict__ bucket,
                int* __restrict__ perm, int* __restrict__ ends) {
    __shared__ int hist[1024];
    __shared__ int cursor[1024];
    __shared__ int sh[512];
    const int tid = threadIdx.x;
    const int b = blockIdx.x;
    const int base = b * BKT_CAP;
    int n = cur[b]; if (n > BKT_CAP) n = BKT_CAP;
    hist[tid] = 0; hist[tid + 512] = 0;
    __syncthreads();
    for (int i = tid; i < n; i += 512)
        atomicAdd(&hist[bucket[base + i] & 1023], 1);
    __syncthreads();
    const int a0 = hist[2 * tid], a1 = hist[2 * tid + 1];
    const int s2 = a0 + a1;
    sh[tid] = s2;
    __syncthreads();
    for (int st = 1; st < 512; st <<= 1) {   // Hillis-Steele inclusive over 512 pair-sums
        int u = (tid >= st) ? sh[tid - st] : 0;
        __syncthreads();
        sh[tid] += u;
        __syncthreads();
    }
    const int excl = sh[tid] - s2;           // exclusive prefix of this thread's pair
    cursor[2 * tid]     = excl;
    cursor[2 * tid + 1] = excl + a0;
    ends[b * 1024 + 2 * tid]     = base + excl + a0;
    ends[b * 1024 + 2 * tid + 1] = base + excl + a0 + a1;
    __syncthreads();
    for (int i = tid; i < n; i += 512) {
        const uint32_t e = bucket[base + i];
        const int pos = atomicAdd(&cursor[e & 1023], 1);
        perm[base + pos] = (int)(e >> 10);
    }
}

// ======================= shared helpers =======================

// x fp32 -> bf16 (flat copy of N*128 elements)
__global__ void xconv_kernel(const float* __restrict__ x, short* __restrict__ xb) {
    int g = blockIdx.x * 256 + threadIdx.x;       // one per 8 elements
    if (g >= N_NODES * CH / 8) return;
    const float4* xp = (const float4*)x;
    float4 a = xp[(size_t)g * 2], b = xp[(size_t)g * 2 + 1];
    frag_ab f;
    f[0] = f2bs(a.x); f[1] = f2bs(a.y); f[2] = f2bs(a.z); f[3] = f2bs(a.w);
    f[4] = f2bs(b.x); f[5] = f2bs(b.y); f[6] = f2bs(b.z); f[7] = f2bs(b.w);
    *(frag_ab*)(xb + (size_t)g * 8) = f;
}

// build swizzled bf16 B: Bsw[chunk][entry][8], entry = ((ks*4+quad)*8+ct)*16+m16
__global__ void bconv_kernel(const float* __restrict__ root, const float* __restrict__ W,
                             short* __restrict__ Bsw) {
    int g = blockIdx.x * 256 + threadIdx.x;
    if (g >= 9 * 2048) return;
    int chunk = g >> 11, entry = g & 2047;
    int m16 = entry & 15, ct = (entry >> 4) & 7, quad = (entry >> 7) & 3, ks = entry >> 9;
    const float* src = (chunk == 0) ? root : W + (size_t)(chunk - 1) * CH * CH;
    int col = ct * 16 + m16, kb = ks * 32 + quad * 8;
    frag_ab f;
#pragma unroll
    for (int j = 0; j < 8; ++j) f[j] = f2bs(src[(size_t)(kb + j) * CH + col]);
    *(frag_ab*)(Bsw + (size_t)g * 8) = f;
}

// ======================= FUSED aggregate + GEMM =======================
// One block = 128 output rows = one coarse bucket. Per relation r: aggregate the
// 128 mean rows into a 32 KB LDS bf16 A-tile (16B-granule XOR swizzle), then MFMA
// chunk r+1 into persistent accumulators. Chunk 0 (root) reads A from global xb.
// Aggregation: 8-lane groups (32B/lane), edge-unroll x2, perm prefetch (R2).
#define ACC16(U0, U1)                                           \
    do {                                                        \
        a0 += bf_lo((U0).x);  a1 += bf_hi((U0).x);              \
        a2 += bf_lo((U0).y);  a3 += bf_hi((U0).y);              \
        a4 += bf_lo((U0).z);  a5 += bf_hi((U0).z);              \
        a6 += bf_lo((U0).w);  a7 += bf_hi((U0).w);              \
        a8 += bf_lo((U1).x);  a9 += bf_hi((U1).x);              \
        a10 += bf_lo((U1).y); a11 += bf_hi((U1).y);             \
        a12 += bf_lo((U1).z); a13 += bf_hi((U1).z);             \
        a14 += bf_lo((U1).w); a15 += bf_hi((U1).w);             \
    } while (0)

__global__ __launch_bounds__(512, 4)
void rgcn_fused(const int* __restrict__ ends, const int* __restrict__ perm,
                const short* __restrict__ xb, const short* __restrict__ Bsw,
                const float* __restrict__ bias, float* __restrict__ out) {
    __shared__ short Ash[128 * 128];   // 32 KB bf16 A-tile, swizzled: chunk16 ^= (row&7)
    __shared__ int lends[1026];        // [bucket_base, ends[b*1024 .. b*1024+1023]]
    const int tid = threadIdx.x;
    const int wave = tid >> 6, lane = tid & 63;
    const int m16 = lane & 15, quad = lane >> 4;
    const int grp = lane >> 3, sub = lane & 7;   // 8-lane gather groups
    const int wm = wave >> 2, wn = wave & 3;     // wave tile: 64 rows x 32 cols
    const long B0 = (long)blockIdx.x * 128;

    // segment boundaries: lends[0] = bucket region base; lends[1+k] = abs end of key k
    for (int i = tid; i < 1025; i += 512)
        lends[i] = (i == 0) ? (int)(blockIdx.x * BKT_CAP)
                            : ends[(size_t)blockIdx.x * 1024 + i - 1];

    float bcol[2];
#pragma unroll
    for (int ct = 0; ct < 2; ++ct) bcol[ct] = bias[wn * 32 + ct * 16 + m16];

    frag_cd acc[4][2];
#pragma unroll
    for (int mt = 0; mt < 4; ++mt)
#pragma unroll
        for (int ct = 0; ct < 2; ++ct) acc[mt][ct] = (frag_cd){0.f, 0.f, 0.f, 0.f};

    __syncthreads();

    // ---- chunk 0: root weight, A-fragments direct from global xb ----
#pragma unroll
    for (int ks = 0; ks < 4; ++ks) {
        frag_ab af[4];
#pragma unroll
        for (int mt = 0; mt < 4; ++mt)
            af[mt] = *(const frag_ab*)(xb + (B0 + wm * 64 + mt * 16 + m16) * CH + ks * 32 + quad * 8);
#pragma unroll
        for (int ct = 0; ct < 2; ++ct) {
            frag_ab bf = *(const frag_ab*)(Bsw + (size_t)((((ks * 4 + quad) * 8) + wn * 2 + ct) * 16 + m16) * 8);
#pragma unroll
            for (int mt = 0; mt < 4; ++mt)
                acc[mt][ct] = __builtin_amdgcn_mfma_f32_16x16x32_bf16(af[mt], bf, acc[mt][ct], 0, 0, 0);
        }
    }

    const uint32_t ch32 = (uint32_t)sub << 5;    // this lane's 32B channel slice
    const char* xbp = (const char*)xb;

    for (int r = 0; r < N_REL; ++r) {
        // ---- aggregate relation r: each 8-lane group owns one dst row ----
#pragma unroll
        for (int step = 0; step < 2; ++step) {
            const int lrow = (wave << 4) + (step << 3) + grp;   // 0..127 unique per (wave,step,grp)
            const int keyL = lrow * 8 + r;
            const int s = lends[keyL];
            const int e = lends[keyL + 1];
            float a0 = 0.f, a1 = 0.f, a2 = 0.f, a3 = 0.f;
            float a4 = 0.f, a5 = 0.f, a6 = 0.f, a7 = 0.f;
            float a8 = 0.f, a9 = 0.f, a10 = 0.f, a11 = 0.f;
            float a12 = 0.f, a13 = 0.f, a14 = 0.f, a15 = 0.f;
            // prefetch indices for the first edge pair (clamped; harmless dup loads)
            int p0 = perm[(s < e) ? s : 0];
            int p1 = perm[(s + 1 < e) ? s + 1 : ((s < e) ? s : 0)];
            for (int k = s; k < e; k += 2) {
                const char* b0 = xbp + (((size_t)(uint32_t)p0 << 8) | ch32);
                const char* b1 = xbp + (((size_t)(uint32_t)p1 << 8) | ch32);
                const uint4 u0 = *(const uint4*)(b0);
                const uint4 u1 = *(const uint4*)(b0 + 16);
                const uint4 u2 = *(const uint4*)(b1);
                const uint4 u3 = *(const uint4*)(b1 + 16);
                const int kn = k + 2;
                p0 = perm[(kn < e) ? kn : 0];                  // prefetch next pair
                p1 = perm[(kn + 1 < e) ? kn + 1 : 0];
                ACC16(u0, u1);
                if (k + 1 < e) ACC16(u2, u3);
            }
            const int c = e - s;
            const float sc = (c > 1) ? (1.0f / (float)c) : 1.0f;
            uint4 w0, w1;
            w0.x = pack2bf(a0 * sc, a1 * sc);
            w0.y = pack2bf(a2 * sc, a3 * sc);
            w0.z = pack2bf(a4 * sc, a5 * sc);
            w0.w = pack2bf(a6 * sc, a7 * sc);
            w1.x = pack2bf(a8 * sc, a9 * sc);
            w1.y = pack2bf(a10 * sc, a11 * sc);
            w1.z = pack2bf(a12 * sc, a13 * sc);
            w1.w = pack2bf(a14 * sc, a15 * sc);
            // swizzled A-tile write (empty segment -> zeros, every row gets written)
            char* drow = (char*)Ash + lrow * 256;
            const int swz = lrow & 7;
            *(uint4*)(drow + ((((sub << 1)    ) ^ swz) << 4)) = w0;
            *(uint4*)(drow + ((((sub << 1) | 1) ^ swz) << 4)) = w1;
        }
        __syncthreads();
        // ---- MFMA chunk r+1: A from LDS (swizzled ds_read_b128), B from L2-hot Bsw ----
        const short* Bc = Bsw + (size_t)(r + 1) * 2048 * 8;
#pragma unroll
        for (int ks = 0; ks < 4; ++ks) {
            frag_ab af[4];
#pragma unroll
            for (int mt = 0; mt < 4; ++mt) {
                const int lr = wm * 64 + mt * 16 + m16;
                af[mt] = *(const frag_ab*)((const char*)Ash + lr * 256 + (((ks * 4 + quad) ^ (lr & 7)) << 4));
            }
#pragma unroll
            for (int ct = 0; ct < 2; ++ct) {
                frag_ab bf = *(const frag_ab*)(Bc + (size_t)((((ks * 4 + quad) * 8) + wn * 2 + ct) * 16 + m16) * 8);
#pragma unroll
                for (int mt = 0; mt < 4; ++mt)
                    acc[mt][ct] = __builtin_amdgcn_mfma_f32_16x16x32_bf16(af[mt], bf, acc[mt][ct], 0, 0, 0);
            }
        }
        __syncthreads();
    }

    // ---- epilogue ----
#pragma unroll
    for (int mt = 0; mt < 4; ++mt) {
#pragma unroll
        for (int ct = 0; ct < 2; ++ct) {
            const long row0 = B0 + wm * 64 + mt * 16 + quad * 4;
            const int col = wn * 32 + ct * 16 + m16;
#pragma unroll
            for (int rg = 0; rg < 4; ++rg) {
                const long rr = row0 + rg;
                if (rr < N_NODES) out[rr * CH + col] = acc[mt][ct][rg] + bcol[ct];
            }
        }
    }
}

// ======================= fallback tiers (round-1 code) =======================

__global__ void count_rd_kernel(const int* __restrict__ ei, const int* __restrict__ et,
                                int* __restrict__ cnt) {
    int e = blockIdx.x * 256 + threadIdx.x;
    if (e < N_EDGES) {
        int dst = ei[N_EDGES + e];
        int r = et[e];
        atomicAdd(&cnt[r * N_NODES + dst], 1);
    }
}

__global__ void scatter_kernel(const int* __restrict__ ei, const int* __restrict__ et,
                               const float* __restrict__ x, float* __restrict__ sums,
                               int rel) {
    int gid = (blockIdx.x * 256 + threadIdx.x) >> 5;
    int lane = threadIdx.x & 31;
    int ngroups = gridDim.x * 8;
    for (int e = gid; e < N_EDGES; e += ngroups) {
        if (et[e] != rel) continue;
        int src = ei[e];
        int dst = ei[N_EDGES + e];
        float4 v = ((const float4*)(x + (size_t)src * CH))[lane];
        float* s = sums + (size_t)dst * CH + (size_t)lane * 4;
        atomicAdd(s + 0, v.x);
        atomicAdd(s + 1, v.y);
        atomicAdd(s + 2, v.z);
        atomicAdd(s + 3, v.w);
    }
}

__global__ __launch_bounds__(256, 2)
void gemm_kernel(const float* __restrict__ A, const float* __restrict__ B,
                 const float* __restrict__ bias, const int* __restrict__ cnt,
                 float* __restrict__ out, int accumulate) {
    const int wave = threadIdx.x >> 6;
    const int lane = threadIdx.x & 63;
    const int m16 = lane & 15;
    const int quad = lane >> 4;

    frag_ab bfrag[4][8];
#pragma unroll
    for (int ks = 0; ks < 4; ++ks) {
        const int kb = ks * 32 + quad * 8;
#pragma unroll
        for (int ct = 0; ct < 8; ++ct) {
            const int col = ct * 16 + m16;
            frag_ab f;
#pragma unroll
            for (int j = 0; j < 8; ++j)
                f[j] = f2bs(B[(size_t)(kb + j) * CH + col]);
            bfrag[ks][ct] = f;
        }
    }

    const int nstrips = (N_NODES + 63) / 64;
    for (int strip = blockIdx.x; strip < nstrips; strip += gridDim.x) {
        const int row = strip * 64 + wave * 16 + m16;
        const bool valid = row < N_NODES;
        float scale = 1.0f;
        if (cnt != nullptr && valid) {
            int c = cnt[row];
            if (c > 1) scale = 1.0f / (float)c;
        }
        const float4* arow = (const float4*)(A + (size_t)(valid ? row : 0) * CH);
        frag_cd acc[8];
#pragma unroll
        for (int ct = 0; ct < 8; ++ct) acc[ct] = (frag_cd){0.f, 0.f, 0.f, 0.f};
#pragma unroll
        for (int ks = 0; ks < 4; ++ks) {
            float4 a0 = arow[ks * 8 + quad * 2];
            float4 a1 = arow[ks * 8 + quad * 2 + 1];
            frag_ab af;
            af[0] = f2bs(a0.x * scale); af[1] = f2bs(a0.y * scale);
            af[2] = f2bs(a0.z * scale); af[3] = f2bs(a0.w * scale);
            af[4] = f2bs(a1.x * scale); af[5] = f2bs(a1.y * scale);
            af[6] = f2bs(a1.z * scale); af[7] = f2bs(a1.w * scale);
#pragma unroll
            for (int ct = 0; ct < 8; ++ct)
                acc[ct] = __builtin_amdgcn_mfma_f32_16x16x32_bf16(af, bfrag[ks][ct], acc[ct], 0, 0, 0);
        }
        const int obase = strip * 64 + wave * 16 + quad * 4;
#pragma unroll
        for (int ct = 0; ct < 8; ++ct) {
            const int col = ct * 16 + m16;
#pragma unroll
            for (int rg = 0; rg < 4; ++rg) {
                const int r = obase + rg;
                if (r < N_NODES) {
                    const size_t idx = (size_t)r * CH + col;
                    if (accumulate) out[idx] += acc[ct][rg];
                    else out[idx] = acc[ct][rg] + bias[col];
                }
            }
        }
    }
}

__global__ void edge_transform_kernel(const int* __restrict__ ei, const int* __restrict__ et,
                                      const float* __restrict__ x, const float* __restrict__ W,
                                      const int* __restrict__ cnt, float* __restrict__ out) {
    __shared__ float xs[CH];
    const int tid = threadIdx.x;
    for (int e = blockIdx.x; e < N_EDGES; e += gridDim.x) {
        const int src = ei[e];
        const int dst = ei[N_EDGES + e];
        const int r = et[e];
        __syncthreads();
        xs[tid] = x[(size_t)src * CH + tid];
        __syncthreads();
        const int c = cnt[r * N_NODES + dst];
        const float scale = (c > 1) ? (1.0f / (float)c) : 1.0f;
        const float* Wr = W + (size_t)r * CH * CH;
        float acc = 0.f;
#pragma unroll 8
        for (int k = 0; k < CH; ++k) acc += xs[k] * Wr[(size_t)k * CH + tid];
        atomicAdd(&out[(size_t)dst * CH + tid], acc * scale);
    }
}

// ======================= launch =======================

static inline size_t al512(size_t x) { return (x + 511) & ~(size_t)511; }

extern "C" void kernel_launch(void* const* d_in, const int* in_sizes, int n_in,
                              void* d_out, int out_size, void* d_ws, size_t ws_size,
                              hipStream_t stream) {
    const float* x    = (const float*)d_in[0];
    const int*   ei   = (const int*)d_in[1];   // [2, E]: row0=src, row1=dst
    const int*   et   = (const int*)d_in[2];   // [E]
    const float* W    = (const float*)d_in[3]; // [R,128,128]
    const float* root = (const float*)d_in[4]; // [128,128]
    const float* bias = (const float*)d_in[5]; // [128]
    float* out = (float*)d_out;

    // ---- tier-1 workspace layout (coarse buckets + in-LDS binning) ----
    size_t o = 0;
    const size_t o_cur  = o; o += al512((size_t)NBKT * 4);
    const size_t o_bkt  = o; o += al512((size_t)NBKT * BKT_CAP * 4);   // 12.8 MB
    const size_t o_perm = o; o += al512((size_t)NBKT * BKT_CAP * 4);   // 12.8 MB
    const size_t o_ends = o; o += al512((size_t)N_KEYS_PAD * 4);       // 3.2 MB
    const size_t o_bsw  = o; o += al512((size_t)9 * 2048 * 16);
    const size_t o_xb   = o; o += al512((size_t)N_PAD * CH * 2);       // 25.6 MB
    const size_t need_t1 = o;

    const size_t cnt_bytes = (size_t)N_REL * N_NODES * sizeof(int);
    const size_t cnt_rsv   = al512(cnt_bytes);
    const size_t sums51    = (size_t)N_NODES * CH * sizeof(float);

    char* ws = (char*)d_ws;
    if (ws_size >= need_t1) {
        int*      cur    = (int*)(ws + o_cur);
        uint32_t* bucket = (uint32_t*)(ws + o_bkt);
        int*      perm   = (int*)(ws + o_perm);
        int*      endsA  = (int*)(ws + o_ends);
        short*    Bsw    = (short*)(ws + o_bsw);
        short*    xb     = (short*)(ws + o_xb);

        hipMemsetAsync(cur, 0, (size_t)NBKT * 4, stream);
        bucket_scatter<<<(N_EDGES + 255) / 256, 256, 0, stream>>>(ei, et, cur, bucket);
        bin_kernel<<<NBKT, 512, 0, stream>>>(cur, bucket, perm, endsA);
        xconv_kernel<<<(N_NODES * CH / 8 + 255) / 256, 256, 0, stream>>>(x, xb);
        bconv_kernel<<<(9 * 2048 + 255) / 256, 256, 0, stream>>>(root, W, Bsw);
        rgcn_fused<<<NBKT, 512, 0, stream>>>(endsA, perm, xb, Bsw, bias, out);
    } else if (ws_size >= cnt_rsv + sums51) {
        int*   cnt  = (int*)d_ws;
        float* sums = (float*)((char*)d_ws + cnt_rsv);
        hipMemsetAsync(cnt, 0, cnt_bytes, stream);
        count_rd_kernel<<<(N_EDGES + 255) / 256, 256, 0, stream>>>(ei, et, cnt);
        gemm_kernel<<<512, 256, 0, stream>>>(x, root, bias, nullptr, out, 0);
        for (int r = 0; r < N_REL; ++r) {
            hipMemsetAsync(sums, 0, sums51, stream);
            scatter_kernel<<<6400, 256, 0, stream>>>(ei, et, x, sums, r);
            gemm_kernel<<<512, 256, 0, stream>>>(sums, W + (size_t)r * CH * CH,
                                                 nullptr, cnt + (size_t)r * N_NODES, out, 1);
        }
    } else {
        int* cnt = (int*)d_ws;
        hipMemsetAsync(cnt, 0, cnt_bytes, stream);
        count_rd_kernel<<<(N_EDGES + 255) / 256, 256, 0, stream>>>(ei, et, cnt);
        gemm_kernel<<<512, 256, 0, stream>>>(x, root, bias, nullptr, out, 0);
        edge_transform_kernel<<<65536, CH, 0, stream>>>(ei, et, x, W, cnt, out);
    }
}

// Round 4
// 327.502 us; speedup vs baseline: 1.9519x; 1.9519x over previous
//
#include <hip/hip_runtime.h>
#include <hip/hip_bf16.h>
#include <stdint.h>

#define N_NODES 100000
#define N_EDGES 1600000
#define CH 128
#define N_REL 8
#define N_PAD 100096            // N_NODES rounded up to multiple of 128 (GEMM strip pad)
#define N_KEYS (N_NODES * N_REL)

#define NBKT 782                // N_PAD / 128 coarse buckets (= fused grid)
#define NSUB 64                 // sub-cursors per bucket (contention spreading)
#define SUBCAP 128              // per-(bucket,sub) capacity; mean 32, sigma 5.7
#define BKT_STRIDE (NSUB * SUBCAP)   // 8192 entries per bucket region
#define CUR_PAD 16              // pad each cursor to a 64B line (R3 lesson:
                                // same-address/line device atomics serialize at ~180ns)
#define N_KEYS_PAD (NBKT * 1024)

using frag_ab = __attribute__((ext_vector_type(8))) short;  // 8 bf16
using frag_cd = __attribute__((ext_vector_type(4))) float;  // 4 fp32

__device__ __forceinline__ short f2bs(float f) {
    union { __hip_bfloat16 h; short s; } u;
    u.h = __float2bfloat16(f);
    return u.s;
}

__device__ __forceinline__ uint32_t pack2bf(float a, float b) {
    union { __hip_bfloat16 h; unsigned short s; } ua, ub;
    ua.h = __float2bfloat16(a); ub.h = __float2bfloat16(b);
    return (uint32_t)ua.s | ((uint32_t)ub.s << 16);
}

__device__ __forceinline__ float bf_lo(uint32_t u) { return __uint_as_float(u << 16); }
__device__ __forceinline__ float bf_hi(uint32_t u) { return __uint_as_float(u & 0xffff0000u); }

// ======================= TIER 1 prologue =======================
// R4: one merged prep kernel (edge scatter + xconv + bconv share the same
// 6250x256 grid; scatter is latency-bound with idle VALU/HBM, so the
// streaming conversions hide under it), then per-bucket LDS binning.

// one packed entry per edge: src<<10 | (dst&127)<<3 | rel
__global__ __launch_bounds__(256)
void prep_kernel(const int* __restrict__ ei, const int* __restrict__ et,
                 int* __restrict__ cur, uint32_t* __restrict__ bucket,
                 const float* __restrict__ x, short* __restrict__ xb,
                 const float* __restrict__ root, const float* __restrict__ W,
                 short* __restrict__ Bsw) {
    const int tid = threadIdx.x;
    const int g = blockIdx.x * 256 + tid;

    // --- edge scatter into (bucket, sub) regions; 64 spread cursors/bucket ---
    if (g < N_EDGES) {
        int dst = ei[N_EDGES + g];
        int src = ei[g];
        int r = et[g];
        int b = dst >> 7;
        int sub = blockIdx.x & (NSUB - 1);
        int pos = atomicAdd(&cur[(sub * NBKT + b) * CUR_PAD], 1);
        if (pos < SUBCAP)
            bucket[((size_t)b * NSUB + sub) * SUBCAP + pos] =
                ((uint32_t)src << 10) | ((uint32_t)(dst & 127) << 3) | (uint32_t)r;
    }

    // --- xconv: x fp32 -> bf16, 8 elements per thread ---
    if (g < N_NODES * CH / 8) {
        const float4* xp = (const float4*)x;
        float4 a = xp[(size_t)g * 2], bb = xp[(size_t)g * 2 + 1];
        frag_ab f;
        f[0] = f2bs(a.x); f[1] = f2bs(a.y); f[2] = f2bs(a.z); f[3] = f2bs(a.w);
        f[4] = f2bs(bb.x); f[5] = f2bs(bb.y); f[6] = f2bs(bb.z); f[7] = f2bs(bb.w);
        *(frag_ab*)(xb + (size_t)g * 8) = f;
    }

    // --- bconv: swizzled bf16 B, entry = ((ks*4+quad)*8+ct)*16+m16 ---
    if (g < 9 * 2048) {
        int chunk = g >> 11, entry = g & 2047;
        int m16 = entry & 15, ct = (entry >> 4) & 7, quad = (entry >> 7) & 3, ks = entry >> 9;
        const float* src = (chunk == 0) ? root : W + (size_t)(chunk - 1) * CH * CH;
        int col = ct * 16 + m16, kb = ks * 32 + quad * 8;
        frag_ab f;
#pragma unroll
        for (int j = 0; j < 8; ++j) f[j] = f2bs(src[(size_t)(kb + j) * CH + col]);
        *(frag_ab*)(Bsw + (size_t)g * 8) = f;
    }
}

// per bucket: LDS histogram over 1024 local keys (entries spread across 64
// padded sub-regions), LDS scan, LDS-cursor scatter. Writes sorted perm (src
// ids) into [b*BKT_STRIDE, b*BKT_STRIDE+n) and absolute segment ENDS.
__global__ __launch_bounds__(512)
void bin_kernel(const int* __restrict__ cur, const uint32_t* __restrict__ bucket,
                int* __restrict__ perm, int* __restrict__ ends) {
    __shared__ int hist[1024];
    __shared__ int cursor[1024];
    __shared__ int sh[512];
    __shared__ int lens[NSUB];
    const int tid = threadIdx.x;
    const int b = blockIdx.x;
    const size_t bbase = (size_t)b * BKT_STRIDE;
    hist[tid] = 0; hist[tid + 512] = 0;
    if (tid < NSUB) {
        int n = cur[(tid * NBKT + b) * CUR_PAD];
        lens[tid] = (n > SUBCAP) ? SUBCAP : n;
    }
    __syncthreads();
    for (int j = tid; j < BKT_STRIDE; j += 512) {
        const int sub = j >> 7;              // j / SUBCAP
        const int i = j & (SUBCAP - 1);
        if (i < lens[sub])
            atomicAdd(&hist[bucket[bbase + j] & 1023], 1);
    }
    __syncthreads();
    const int a0 = hist[2 * tid], a1 = hist[2 * tid + 1];
    const int s2 = a0 + a1;
    sh[tid] = s2;
    __syncthreads();
    for (int st = 1; st < 512; st <<= 1) {   // Hillis-Steele inclusive over 512 pair-sums
        int u = (tid >= st) ? sh[tid - st] : 0;
        __syncthreads();
        sh[tid] += u;
        __syncthreads();
    }
    const int excl = sh[tid] - s2;           // exclusive prefix of this thread's pair
    cursor[2 * tid]     = excl;
    cursor[2 * tid + 1] = excl + a0;
    ends[b * 1024 + 2 * tid]     = (int)bbase + excl + a0;
    ends[b * 1024 + 2 * tid + 1] = (int)bbase + excl + a0 + a1;
    __syncthreads();
    for (int j = tid; j < BKT_STRIDE; j += 512) {
        const int sub = j >> 7;
        const int i = j & (SUBCAP - 1);
        if (i < lens[sub]) {
            const uint32_t e = bucket[bbase + j];
            const int pos = atomicAdd(&cursor[e & 1023], 1);
            perm[bbase + pos] = (int)(e >> 10);
        }
    }
}

// ======================= FUSED aggregate + GEMM =======================
// One block = 128 output rows = one coarse bucket. Per relation r: aggregate the
// 128 mean rows into a 32 KB LDS bf16 A-tile (16B-granule XOR swizzle), then MFMA
// chunk r+1 into persistent accumulators. Chunk 0 (root) reads A from global xb.
// Aggregation: 8-lane groups (32B/lane), edge-unroll x2, perm prefetch (R2).
#define ACC16(U0, U1)                                           \
    do {                                                        \
        a0 += bf_lo((U0).x);  a1 += bf_hi((U0).x);              \
        a2 += bf_lo((U0).y);  a3 += bf_hi((U0).y);              \
        a4 += bf_lo((U0).z);  a5 += bf_hi((U0).z);              \
        a6 += bf_lo((U0).w);  a7 += bf_hi((U0).w);              \
        a8 += bf_lo((U1).x);  a9 += bf_hi((U1).x);              \
        a10 += bf_lo((U1).y); a11 += bf_hi((U1).y);             \
        a12 += bf_lo((U1).z); a13 += bf_hi((U1).z);             \
        a14 += bf_lo((U1).w); a15 += bf_hi((U1).w);             \
    } while (0)

__global__ __launch_bounds__(512, 4)
void rgcn_fused(const int* __restrict__ ends, const int* __restrict__ perm,
                const short* __restrict__ xb, const short* __restrict__ Bsw,
                const float* __restrict__ bias, float* __restrict__ out) {
    __shared__ short Ash[128 * 128];   // 32 KB bf16 A-tile, swizzled: chunk16 ^= (row&7)
    __shared__ int lends[1026];        // [bucket_base, ends[b*1024 .. b*1024+1023]]
    const int tid = threadIdx.x;
    const int wave = tid >> 6, lane = tid & 63;
    const int m16 = lane & 15, quad = lane >> 4;
    const int grp = lane >> 3, sub = lane & 7;   // 8-lane gather groups
    const int wm = wave >> 2, wn = wave & 3;     // wave tile: 64 rows x 32 cols
    const long B0 = (long)blockIdx.x * 128;

    // segment boundaries: lends[0] = bucket region base; lends[1+k] = abs end of key k
    for (int i = tid; i < 1025; i += 512)
        lends[i] = (i == 0) ? (int)(blockIdx.x * BKT_STRIDE)
                            : ends[(size_t)blockIdx.x * 1024 + i - 1];

    float bcol[2];
#pragma unroll
    for (int ct = 0; ct < 2; ++ct) bcol[ct] = bias[wn * 32 + ct * 16 + m16];

    frag_cd acc[4][2];
#pragma unroll
    for (int mt = 0; mt < 4; ++mt)
#pragma unroll
        for (int ct = 0; ct < 2; ++ct) acc[mt][ct] = (frag_cd){0.f, 0.f, 0.f, 0.f};

    __syncthreads();

    // ---- chunk 0: root weight, A-fragments direct from global xb ----
#pragma unroll
    for (int ks = 0; ks < 4; ++ks) {
        frag_ab af[4];
#pragma unroll
        for (int mt = 0; mt < 4; ++mt)
            af[mt] = *(const frag_ab*)(xb + (B0 + wm * 64 + mt * 16 + m16) * CH + ks * 32 + quad * 8);
#pragma unroll
        for (int ct = 0; ct < 2; ++ct) {
            frag_ab bf = *(const frag_ab*)(Bsw + (size_t)((((ks * 4 + quad) * 8) + wn * 2 + ct) * 16 + m16) * 8);
#pragma unroll
            for (int mt = 0; mt < 4; ++mt)
                acc[mt][ct] = __builtin_amdgcn_mfma_f32_16x16x32_bf16(af[mt], bf, acc[mt][ct], 0, 0, 0);
        }
    }

    const uint32_t ch32 = (uint32_t)sub << 5;    // this lane's 32B channel slice
    const char* xbp = (const char*)xb;

    for (int r = 0; r < N_REL; ++r) {
        // ---- aggregate relation r: each 8-lane group owns one dst row ----
#pragma unroll
        for (int step = 0; step < 2; ++step) {
            const int lrow = (wave << 4) + (step << 3) + grp;   // 0..127 unique per (wave,step,grp)
            const int keyL = lrow * 8 + r;
            const int s = lends[keyL];
            const int e = lends[keyL + 1];
            float a0 = 0.f, a1 = 0.f, a2 = 0.f, a3 = 0.f;
            float a4 = 0.f, a5 = 0.f, a6 = 0.f, a7 = 0.f;
            float a8 = 0.f, a9 = 0.f, a10 = 0.f, a11 = 0.f;
            float a12 = 0.f, a13 = 0.f, a14 = 0.f, a15 = 0.f;
            // prefetch indices for the first edge pair (clamped; harmless dup loads)
            int p0 = perm[(s < e) ? s : 0];
            int p1 = perm[(s + 1 < e) ? s + 1 : ((s < e) ? s : 0)];
            for (int k = s; k < e; k += 2) {
                const char* b0 = xbp + (((size_t)(uint32_t)p0 << 8) | ch32);
                const char* b1 = xbp + (((size_t)(uint32_t)p1 << 8) | ch32);
                const uint4 u0 = *(const uint4*)(b0);
                const uint4 u1 = *(const uint4*)(b0 + 16);
                const uint4 u2 = *(const uint4*)(b1);
                const uint4 u3 = *(const uint4*)(b1 + 16);
                const int kn = k + 2;
                p0 = perm[(kn < e) ? kn : 0];                  // prefetch next pair
                p1 = perm[(kn + 1 < e) ? kn + 1 : 0];
                ACC16(u0, u1);
                if (k + 1 < e) ACC16(u2, u3);
            }
            const int c = e - s;
            const float sc = (c > 1) ? (1.0f / (float)c) : 1.0f;
            uint4 w0, w1;
            w0.x = pack2bf(a0 * sc, a1 * sc);
            w0.y = pack2bf(a2 * sc, a3 * sc);
            w0.z = pack2bf(a4 * sc, a5 * sc);
            w0.w = pack2bf(a6 * sc, a7 * sc);
            w1.x = pack2bf(a8 * sc, a9 * sc);
            w1.y = pack2bf(a10 * sc, a11 * sc);
            w1.z = pack2bf(a12 * sc, a13 * sc);
            w1.w = pack2bf(a14 * sc, a15 * sc);
            // swizzled A-tile write (empty segment -> zeros, every row gets written)
            char* drow = (char*)Ash + lrow * 256;
            const int swz = lrow & 7;
            *(uint4*)(drow + ((((sub << 1)    ) ^ swz) << 4)) = w0;
            *(uint4*)(drow + ((((sub << 1) | 1) ^ swz) << 4)) = w1;
        }
        __syncthreads();
        // ---- MFMA chunk r+1: A from LDS (swizzled ds_read_b128), B from L2-hot Bsw ----
        const short* Bc = Bsw + (size_t)(r + 1) * 2048 * 8;
#pragma unroll
        for (int ks = 0; ks < 4; ++ks) {
            frag_ab af[4];
#pragma unroll
            for (int mt = 0; mt < 4; ++mt) {
                const int lr = wm * 64 + mt * 16 + m16;
                af[mt] = *(const frag_ab*)((const char*)Ash + lr * 256 + (((ks * 4 + quad) ^ (lr & 7)) << 4));
            }
#pragma unroll
            for (int ct = 0; ct < 2; ++ct) {
                frag_ab bf = *(const frag_ab*)(Bc + (size_t)((((ks * 4 + quad) * 8) + wn * 2 + ct) * 16 + m16) * 8);
#pragma unroll
                for (int mt = 0; mt < 4; ++mt)
                    acc[mt][ct] = __builtin_amdgcn_mfma_f32_16x16x32_bf16(af[mt], bf, acc[mt][ct], 0, 0, 0);
            }
        }
        __syncthreads();
    }

    // ---- epilogue ----
#pragma unroll
    for (int mt = 0; mt < 4; ++mt) {
#pragma unroll
        for (int ct = 0; ct < 2; ++ct) {
            const long row0 = B0 + wm * 64 + mt * 16 + quad * 4;
            const int col = wn * 32 + ct * 16 + m16;
#pragma unroll
            for (int rg = 0; rg < 4; ++rg) {
                const long rr = row0 + rg;
                if (rr < N_NODES) out[rr * CH + col] = acc[mt][ct][rg] + bcol[ct];
            }
        }
    }
}

// ======================= fallback tiers (round-1 code) =======================

__global__ void count_rd_kernel(const int* __restrict__ ei, const int* __restrict__ et,
                                int* __restrict__ cnt) {
    int e = blockIdx.x * 256 + threadIdx.x;
    if (e < N_EDGES) {
        int dst = ei[N_EDGES + e];
        int r = et[e];
        atomicAdd(&cnt[r * N_NODES + dst], 1);
    }
}

__global__ void scatter_kernel(const int* __restrict__ ei, const int* __restrict__ et,
                               const float* __restrict__ x, float* __restrict__ sums,
                               int rel) {
    int gid = (blockIdx.x * 256 + threadIdx.x) >> 5;
    int lane = threadIdx.x & 31;
    int ngroups = gridDim.x * 8;
    for (int e = gid; e < N_EDGES; e += ngroups) {
        if (et[e] != rel) continue;
        int src = ei[e];
        int dst = ei[N_EDGES + e];
        float4 v = ((const float4*)(x + (size_t)src * CH))[lane];
        float* s = sums + (size_t)dst * CH + (size_t)lane * 4;
        atomicAdd(s + 0, v.x);
        atomicAdd(s + 1, v.y);
        atomicAdd(s + 2, v.z);
        atomicAdd(s + 3, v.w);
    }
}

__global__ __launch_bounds__(256, 2)
void gemm_kernel(const float* __restrict__ A, const float* __restrict__ B,
                 const float* __restrict__ bias, const int* __restrict__ cnt,
                 float* __restrict__ out, int accumulate) {
    const int wave = threadIdx.x >> 6;
    const int lane = threadIdx.x & 63;
    const int m16 = lane & 15;
    const int quad = lane >> 4;

    frag_ab bfrag[4][8];
#pragma unroll
    for (int ks = 0; ks < 4; ++ks) {
        const int kb = ks * 32 + quad * 8;
#pragma unroll
        for (int ct = 0; ct < 8; ++ct) {
            const int col = ct * 16 + m16;
            frag_ab f;
#pragma unroll
            for (int j = 0; j < 8; ++j)
                f[j] = f2bs(B[(size_t)(kb + j) * CH + col]);
            bfrag[ks][ct] = f;
        }
    }

    const int nstrips = (N_NODES + 63) / 64;
    for (int strip = blockIdx.x; strip < nstrips; strip += gridDim.x) {
        const int row = strip * 64 + wave * 16 + m16;
        const bool valid = row < N_NODES;
        float scale = 1.0f;
        if (cnt != nullptr && valid) {
            int c = cnt[row];
            if (c > 1) scale = 1.0f / (float)c;
        }
        const float4* arow = (const float4*)(A + (size_t)(valid ? row : 0) * CH);
        frag_cd acc[8];
#pragma unroll
        for (int ct = 0; ct < 8; ++ct) acc[ct] = (frag_cd){0.f, 0.f, 0.f, 0.f};
#pragma unroll
        for (int ks = 0; ks < 4; ++ks) {
            float4 a0 = arow[ks * 8 + quad * 2];
            float4 a1 = arow[ks * 8 + quad * 2 + 1];
            frag_ab af;
            af[0] = f2bs(a0.x * scale); af[1] = f2bs(a0.y * scale);
            af[2] = f2bs(a0.z * scale); af[3] = f2bs(a0.w * scale);
            af[4] = f2bs(a1.x * scale); af[5] = f2bs(a1.y * scale);
            af[6] = f2bs(a1.z * scale); af[7] = f2bs(a1.w * scale);
#pragma unroll
            for (int ct = 0; ct < 8; ++ct)
                acc[ct] = __builtin_amdgcn_mfma_f32_16x16x32_bf16(af, bfrag[ks][ct], acc[ct], 0, 0, 0);
        }
        const int obase = strip * 64 + wave * 16 + quad * 4;
#pragma unroll
        for (int ct = 0; ct < 8; ++ct) {
            const int col = ct * 16 + m16;
#pragma unroll
            for (int rg = 0; rg < 4; ++rg) {
                const int r = obase + rg;
                if (r < N_NODES) {
                    const size_t idx = (size_t)r * CH + col;
                    if (accumulate) out[idx] += acc[ct][rg];
                    else out[idx] = acc[ct][rg] + bias[col];
                }
            }
        }
    }
}

__global__ void edge_transform_kernel(const int* __restrict__ ei, const int* __restrict__ et,
                                      const float* __restrict__ x, const float* __restrict__ W,
                                      const int* __restrict__ cnt, float* __restrict__ out) {
    __shared__ float xs[CH];
    const int tid = threadIdx.x;
    for (int e = blockIdx.x; e < N_EDGES; e += gridDim.x) {
        const int src = ei[e];
        const int dst = ei[N_EDGES + e];
        const int r = et[e];
        __syncthreads();
        xs[tid] = x[(size_t)src * CH + tid];
        __syncthreads();
        const int c = cnt[r * N_NODES + dst];
        const float scale = (c > 1) ? (1.0f / (float)c) : 1.0f;
        const float* Wr = W + (size_t)r * CH * CH;
        float acc = 0.f;
#pragma unroll 8
        for (int k = 0; k < CH; ++k) acc += xs[k] * Wr[(size_t)k * CH + tid];
        atomicAdd(&out[(size_t)dst * CH + tid], acc * scale);
    }
}

// ======================= launch =======================

static inline size_t al512(size_t x) { return (x + 511) & ~(size_t)511; }

extern "C" void kernel_launch(void* const* d_in, const int* in_sizes, int n_in,
                              void* d_out, int out_size, void* d_ws, size_t ws_size,
                              hipStream_t stream) {
    const float* x    = (const float*)d_in[0];
    const int*   ei   = (const int*)d_in[1];   // [2, E]: row0=src, row1=dst
    const int*   et   = (const int*)d_in[2];   // [E]
    const float* W    = (const float*)d_in[3]; // [R,128,128]
    const float* root = (const float*)d_in[4]; // [128,128]
    const float* bias = (const float*)d_in[5]; // [128]
    float* out = (float*)d_out;

    // ---- tier-1 workspace layout (coarse buckets, spread cursors) ----
    size_t o = 0;
    const size_t o_cur  = o; o += al512((size_t)NSUB * NBKT * CUR_PAD * 4);  // 3.2 MB
    const size_t o_bkt  = o; o += al512((size_t)NBKT * BKT_STRIDE * 4);      // 25.6 MB
    const size_t o_perm = o; o += al512((size_t)NBKT * BKT_STRIDE * 4);      // 25.6 MB
    const size_t o_ends = o; o += al512((size_t)N_KEYS_PAD * 4);             // 3.2 MB
    const size_t o_bsw  = o; o += al512((size_t)9 * 2048 * 16);
    const size_t o_xb   = o; o += al512((size_t)N_PAD * CH * 2);             // 25.6 MB
    const size_t need_t1 = o;

    const size_t cnt_bytes = (size_t)N_REL * N_NODES * sizeof(int);
    const size_t cnt_rsv   = al512(cnt_bytes);
    const size_t sums51    = (size_t)N_NODES * CH * sizeof(float);

    char* ws = (char*)d_ws;
    if (ws_size >= need_t1) {
        int*      cur    = (int*)(ws + o_cur);
        uint32_t* bucket = (uint32_t*)(ws + o_bkt);
        int*      perm   = (int*)(ws + o_perm);
        int*      endsA  = (int*)(ws + o_ends);
        short*    Bsw    = (short*)(ws + o_bsw);
        short*    xb     = (short*)(ws + o_xb);

        hipMemsetAsync(cur, 0, (size_t)NSUB * NBKT * CUR_PAD * 4, stream);
        prep_kernel<<<(N_EDGES + 255) / 256, 256, 0, stream>>>(
            ei, et, cur, bucket, x, xb, root, W, Bsw);
        bin_kernel<<<NBKT, 512, 0, stream>>>(cur, bucket, perm, endsA);
        rgcn_fused<<<NBKT, 512, 0, stream>>>(endsA, perm, xb, Bsw, bias, out);
    } else if (ws_size >= cnt_rsv + sums51) {
        int*   cnt  = (int*)d_ws;
        float* sums = (float*)((char*)d_ws + cnt_rsv);
        hipMemsetAsync(cnt, 0, cnt_bytes, stream);
        count_rd_kernel<<<(N_EDGES + 255) / 256, 256, 0, stream>>>(ei, et, cnt);
        gemm_kernel<<<512, 256, 0, stream>>>(x, root, bias, nullptr, out, 0);
        for (int r = 0; r < N_REL; ++r) {
            hipMemsetAsync(sums, 0, sums51, stream);
            scatter_kernel<<<6400, 256, 0, stream>>>(ei, et, x, sums, r);
            gemm_kernel<<<512, 256, 0, stream>>>(sums, W + (size_t)r * CH * CH,
                                                 nullptr, cnt + (size_t)r * N_NODES, out, 1);
        }
    } else {
        int* cnt = (int*)d_ws;
        hipMemsetAsync(cnt, 0, cnt_bytes, stream);
        count_rd_kernel<<<(N_EDGES + 255) / 256, 256, 0, stream>>>(ei, et, cnt);
        gemm_kernel<<<512, 256, 0, stream>>>(x, root, bias, nullptr, out, 0);
        edge_transform_kernel<<<65536, CH, 0, stream>>>(ei, et, x, W, cnt, out);
    }
}

// Round 5
// 325.949 us; speedup vs baseline: 1.9612x; 1.0048x over previous
//
#include <hip/hip_runtime.h>
#include <hip/hip_bf16.h>
#include <stdint.h>

#define N_NODES 100000
#define N_EDGES 1600000
#define CH 128
#define N_REL 8
#define N_PAD 100096            // N_NODES rounded up to multiple of 128
#define N_KEYS (N_NODES * N_REL)

#define NBKT 782                // N_PAD / 128 coarse buckets (= fused grid)
#define NSUB 64                 // sub-cursors per bucket (contention spreading)
#define SUBCAP 128              // per-(bucket,sub) capacity; mean 32, sigma 5.7
#define BKT_STRIDE (NSUB * SUBCAP)   // 8192 entries per bucket region
#define CUR_PAD 16              // pad each cursor to a 64B line (R3 lesson:
                                // same-line device atomics serialize at ~180ns)
#define PERM_LDS_CAP 4096       // per-bucket edges ~2046 +- 45 -> 45-sigma margin

using frag_ab = __attribute__((ext_vector_type(8))) short;  // 8 bf16
using frag_cd = __attribute__((ext_vector_type(4))) float;  // 4 fp32

__device__ __forceinline__ short f2bs(float f) {
    union { __hip_bfloat16 h; short s; } u;
    u.h = __float2bfloat16(f);
    return u.s;
}

__device__ __forceinline__ uint32_t pack2bf(float a, float b) {
    union { __hip_bfloat16 h; unsigned short s; } ua, ub;
    ua.h = __float2bfloat16(a); ub.h = __float2bfloat16(b);
    return (uint32_t)ua.s | ((uint32_t)ub.s << 16);
}

__device__ __forceinline__ float bf_lo(uint32_t u) { return __uint_as_float(u << 16); }
__device__ __forceinline__ float bf_hi(uint32_t u) { return __uint_as_float(u & 0xffff0000u); }

// ======================= prologue: merged prep =======================
// edge scatter (64 spread cursors/bucket) + xconv + bconv share one grid;
// the scatter is latency-bound with idle VALU/HBM, so the streaming
// conversions hide under it (R4, measured).

__global__ __launch_bounds__(256)
void prep_kernel(const int* __restrict__ ei, const int* __restrict__ et,
                 int* __restrict__ cur, uint32_t* __restrict__ bucket,
                 const float* __restrict__ x, short* __restrict__ xb,
                 const float* __restrict__ root, const float* __restrict__ W,
                 short* __restrict__ Bsw) {
    const int tid = threadIdx.x;
    const int g = blockIdx.x * 256 + tid;

    // --- edge scatter into (bucket, sub) regions ---
    if (g < N_EDGES) {
        int dst = ei[N_EDGES + g];
        int src = ei[g];
        int r = et[g];
        int b = dst >> 7;
        int sub = blockIdx.x & (NSUB - 1);
        int pos = atomicAdd(&cur[(sub * NBKT + b) * CUR_PAD], 1);
        if (pos < SUBCAP)
            bucket[((size_t)b * NSUB + sub) * SUBCAP + pos] =
                ((uint32_t)src << 10) | ((uint32_t)(dst & 127) << 3) | (uint32_t)r;
    }

    // --- xconv: x fp32 -> bf16, 8 elements per thread ---
    if (g < N_NODES * CH / 8) {
        const float4* xp = (const float4*)x;
        float4 a = xp[(size_t)g * 2], bb = xp[(size_t)g * 2 + 1];
        frag_ab f;
        f[0] = f2bs(a.x); f[1] = f2bs(a.y); f[2] = f2bs(a.z); f[3] = f2bs(a.w);
        f[4] = f2bs(bb.x); f[5] = f2bs(bb.y); f[6] = f2bs(bb.z); f[7] = f2bs(bb.w);
        *(frag_ab*)(xb + (size_t)g * 8) = f;
    }

    // --- bconv: swizzled bf16 B, entry = ((ks*4+quad)*8+ct)*16+m16 ---
    if (g < 9 * 2048) {
        int chunk = g >> 11, entry = g & 2047;
        int m16 = entry & 15, ct = (entry >> 4) & 7, quad = (entry >> 7) & 3, ks = entry >> 9;
        const float* src = (chunk == 0) ? root : W + (size_t)(chunk - 1) * CH * CH;
        int col = ct * 16 + m16, kb = ks * 32 + quad * 8;
        frag_ab f;
#pragma unroll
        for (int j = 0; j < 8; ++j) f[j] = f2bs(src[(size_t)(kb + j) * CH + col]);
        *(frag_ab*)(Bsw + (size_t)g * 8) = f;
    }
}

// ======================= MEGA: in-LDS binning + aggregate + GEMM =======================
// One block = 128 output rows = one coarse bucket.
// Phase 0: bin the bucket's edges in LDS (hist/scan/scatter; hist+cursor+scan
//          alias the A-tile region, unused until relation 0). perm stays in LDS
//          -> no global perm/ends round-trip, and the gather dependency chain is
//          LDS-read -> gather instead of global-read -> gather.
// Phase r: aggregate relation r into the 32KB swizzled A-tile with 4-lane groups
//          (one dst row per group, 64B/lane, edge-unroll x2 = 8 uint4 in flight
//          per thread: 16x the in-flight bytes of R4's layout, which measured
//          HBM-latency-bound at 1.8 TB/s), then MFMA chunk r+1.
#define ACC_U4(U, B)                                            \
    do {                                                        \
        a[(B)+0] += bf_lo((U).x); a[(B)+1] += bf_hi((U).x);     \
        a[(B)+2] += bf_lo((U).y); a[(B)+3] += bf_hi((U).y);     \
        a[(B)+4] += bf_lo((U).z); a[(B)+5] += bf_hi((U).z);     \
        a[(B)+6] += bf_lo((U).w); a[(B)+7] += bf_hi((U).w);     \
    } while (0)

__global__ __launch_bounds__(512, 4)
void rgcn_mega(const int* __restrict__ cur, const uint32_t* __restrict__ bucket,
               int* __restrict__ perm_spill,
               const short* __restrict__ xb, const short* __restrict__ Bsw,
               const float* __restrict__ bias, float* __restrict__ out) {
    __shared__ short Ash[128 * 128];       // 32 KB A-tile; binned-over during phase 0
    __shared__ int perm_lds[PERM_LDS_CAP]; // 16 KB sorted src ids
    __shared__ int lends[1025];            // local segment ends; lends[0] = 0
    __shared__ int lens[NSUB];
    int* hist   = (int*)Ash;               // [1024]   (alias, phase 0 only)
    int* cursor = (int*)Ash + 1024;        // [1024]
    int* shl    = (int*)Ash + 2048;        // [512]

    const int tid = threadIdx.x;
    const int wave = tid >> 6, lane = tid & 63;
    const int m16 = lane & 15, quad = lane >> 4;
    const int wm = wave >> 2, wn = wave & 3;     // wave tile: 64 rows x 32 cols
    const int b = blockIdx.x;
    const size_t bbase = (size_t)b * BKT_STRIDE;
    const long B0 = (long)b * 128;

#define PERM(idx) (((idx) < PERM_LDS_CAP) ? perm_lds[(idx)] : perm_spill[bbase + (idx)])

    // ---- phase 0a: histogram over this bucket's valid entries ----
    hist[tid] = 0; hist[tid + 512] = 0;
    if (tid == 0) perm_lds[0] = 0;             // safe gather target for empty buckets
    if (tid < NSUB) {
        int n = cur[(tid * NBKT + b) * CUR_PAD];
        lens[tid] = (n > SUBCAP) ? SUBCAP : n;
    }
    __syncthreads();
    for (int j = tid; j < BKT_STRIDE; j += 512)
        if ((j & (SUBCAP - 1)) < lens[j >> 7])
            atomicAdd(&hist[bucket[bbase + j] & 1023], 1);
    __syncthreads();
    // ---- phase 0b: scan (pair-sums, Hillis-Steele over 512) ----
    const int h0 = hist[2 * tid], h1 = hist[2 * tid + 1];
    const int s2 = h0 + h1;
    shl[tid] = s2;
    __syncthreads();
    for (int st = 1; st < 512; st <<= 1) {
        int u = (tid >= st) ? shl[tid - st] : 0;
        __syncthreads();
        shl[tid] += u;
        __syncthreads();
    }
    const int excl = shl[tid] - s2;
    cursor[2 * tid]     = excl;
    cursor[2 * tid + 1] = excl + h0;
    if (tid == 0) lends[0] = 0;
    lends[1 + 2 * tid] = excl + h0;
    lends[2 + 2 * tid] = excl + h0 + h1;
    __syncthreads();
    // ---- phase 0c: scatter into LDS perm ----
    for (int j = tid; j < BKT_STRIDE; j += 512)
        if ((j & (SUBCAP - 1)) < lens[j >> 7]) {
            const uint32_t e = bucket[bbase + j];
            const int pos = atomicAdd(&cursor[e & 1023], 1);
            const int v = (int)(e >> 10);
            if (pos < PERM_LDS_CAP) perm_lds[pos] = v;
            else perm_spill[bbase + pos] = v;
        }

    // ---- chunk 0 (root): A direct from global xb; overlaps the scatter tail ----
    float bcol[2];
#pragma unroll
    for (int ct = 0; ct < 2; ++ct) bcol[ct] = bias[wn * 32 + ct * 16 + m16];

    frag_cd acc[4][2];
#pragma unroll
    for (int mt = 0; mt < 4; ++mt)
#pragma unroll
        for (int ct = 0; ct < 2; ++ct) acc[mt][ct] = (frag_cd){0.f, 0.f, 0.f, 0.f};

#pragma unroll
    for (int ks = 0; ks < 4; ++ks) {
        frag_ab af[4];
#pragma unroll
        for (int mt = 0; mt < 4; ++mt)
            af[mt] = *(const frag_ab*)(xb + (B0 + wm * 64 + mt * 16 + m16) * CH + ks * 32 + quad * 8);
#pragma unroll
        for (int ct = 0; ct < 2; ++ct) {
            frag_ab bf = *(const frag_ab*)(Bsw + (size_t)((((ks * 4 + quad) * 8) + wn * 2 + ct) * 16 + m16) * 8);
#pragma unroll
            for (int mt = 0; mt < 4; ++mt)
                acc[mt][ct] = __builtin_amdgcn_mfma_f32_16x16x32_bf16(af[mt], bf, acc[mt][ct], 0, 0, 0);
        }
    }
    __syncthreads();   // binning done, hist/cursor aliases dead, Ash free

    // ---- relation loop ----
    const int lrow = tid >> 2;                     // 4-lane group -> one dst row
    const int q4 = tid & 3;
    const uint32_t ch64 = (uint32_t)q4 << 6;       // this lane's 64B channel slice
    const char* xbp = (const char*)xb;
    char* drow = (char*)Ash + lrow * 256;
    const int swz = lrow & 7;

    for (int r = 0; r < N_REL; ++r) {
        const int keyL = lrow * 8 + r;
        const int s = lends[keyL];
        const int e = lends[keyL + 1];
        float a[32];
#pragma unroll
        for (int i = 0; i < 32; ++i) a[i] = 0.f;
        int p0 = PERM((s < e) ? s : 0);
        int p1 = PERM((s + 1 < e) ? s + 1 : ((s < e) ? s : 0));
        for (int k = s; k < e; k += 2) {
            const char* c0 = xbp + (((size_t)(uint32_t)p0 << 8) | ch64);
            const char* c1 = xbp + (((size_t)(uint32_t)p1 << 8) | ch64);
            const uint4 u0 = *(const uint4*)(c0);
            const uint4 u1 = *(const uint4*)(c0 + 16);
            const uint4 u2 = *(const uint4*)(c0 + 32);
            const uint4 u3 = *(const uint4*)(c0 + 48);
            const uint4 u4 = *(const uint4*)(c1);
            const uint4 u5 = *(const uint4*)(c1 + 16);
            const uint4 u6 = *(const uint4*)(c1 + 32);
            const uint4 u7 = *(const uint4*)(c1 + 48);
            const bool two = (k + 1 < e);
            const int kn = k + 2;
            p0 = PERM((kn < e) ? kn : 0);
            p1 = PERM((kn + 1 < e) ? kn + 1 : 0);
            ACC_U4(u0, 0); ACC_U4(u1, 8); ACC_U4(u2, 16); ACC_U4(u3, 24);
            if (two) { ACC_U4(u4, 0); ACC_U4(u5, 8); ACC_U4(u6, 16); ACC_U4(u7, 24); }
        }
        const int c = e - s;
        const float sc = (c > 1) ? (1.0f / (float)c) : 1.0f;
#pragma unroll
        for (int t = 0; t < 4; ++t) {
            uint4 w;
            w.x = pack2bf(a[t * 8 + 0] * sc, a[t * 8 + 1] * sc);
            w.y = pack2bf(a[t * 8 + 2] * sc, a[t * 8 + 3] * sc);
            w.z = pack2bf(a[t * 8 + 4] * sc, a[t * 8 + 5] * sc);
            w.w = pack2bf(a[t * 8 + 6] * sc, a[t * 8 + 7] * sc);
            *(uint4*)(drow + (((q4 * 4 + t) ^ swz) << 4)) = w;   // swizzled A-tile write
        }
        __syncthreads();
        // ---- MFMA chunk r+1: A from LDS (swizzled ds_read_b128), B from L2-hot Bsw ----
        const short* Bc = Bsw + (size_t)(r + 1) * 2048 * 8;
#pragma unroll
        for (int ks = 0; ks < 4; ++ks) {
            frag_ab af[4];
#pragma unroll
            for (int mt = 0; mt < 4; ++mt) {
                const int lr = wm * 64 + mt * 16 + m16;
                af[mt] = *(const frag_ab*)((const char*)Ash + lr * 256 + (((ks * 4 + quad) ^ (lr & 7)) << 4));
            }
#pragma unroll
            for (int ct = 0; ct < 2; ++ct) {
                frag_ab bf = *(const frag_ab*)(Bc + (size_t)((((ks * 4 + quad) * 8) + wn * 2 + ct) * 16 + m16) * 8);
#pragma unroll
                for (int mt = 0; mt < 4; ++mt)
                    acc[mt][ct] = __builtin_amdgcn_mfma_f32_16x16x32_bf16(af[mt], bf, acc[mt][ct], 0, 0, 0);
            }
        }
        __syncthreads();
    }
#undef PERM

    // ---- epilogue ----
#pragma unroll
    for (int mt = 0; mt < 4; ++mt) {
#pragma unroll
        for (int ct = 0; ct < 2; ++ct) {
            const long row0 = B0 + wm * 64 + mt * 16 + quad * 4;
            const int col = wn * 32 + ct * 16 + m16;
#pragma unroll
            for (int rg = 0; rg < 4; ++rg) {
                const long rr = row0 + rg;
                if (rr < N_NODES) out[rr * CH + col] = acc[mt][ct][rg] + bcol[ct];
            }
        }
    }
}

// ======================= fallback tiers (round-1 code) =======================

__global__ void count_rd_kernel(const int* __restrict__ ei, const int* __restrict__ et,
                                int* __restrict__ cnt) {
    int e = blockIdx.x * 256 + threadIdx.x;
    if (e < N_EDGES) {
        int dst = ei[N_EDGES + e];
        int r = et[e];
        atomicAdd(&cnt[r * N_NODES + dst], 1);
    }
}

__global__ void scatter_kernel(const int* __restrict__ ei, const int* __restrict__ et,
                               const float* __restrict__ x, float* __restrict__ sums,
                               int rel) {
    int gid = (blockIdx.x * 256 + threadIdx.x) >> 5;
    int lane = threadIdx.x & 31;
    int ngroups = gridDim.x * 8;
    for (int e = gid; e < N_EDGES; e += ngroups) {
        if (et[e] != rel) continue;
        int src = ei[e];
        int dst = ei[N_EDGES + e];
        float4 v = ((const float4*)(x + (size_t)src * CH))[lane];
        float* s = sums + (size_t)dst * CH + (size_t)lane * 4;
        atomicAdd(s + 0, v.x);
        atomicAdd(s + 1, v.y);
        atomicAdd(s + 2, v.z);
        atomicAdd(s + 3, v.w);
    }
}

__global__ __launch_bounds__(256, 2)
void gemm_kernel(const float* __restrict__ A, const float* __restrict__ B,
                 const float* __restrict__ bias, const int* __restrict__ cnt,
                 float* __restrict__ out, int accumulate) {
    const int wave = threadIdx.x >> 6;
    const int lane = threadIdx.x & 63;
    const int m16 = lane & 15;
    const int quad = lane >> 4;

    frag_ab bfrag[4][8];
#pragma unroll
    for (int ks = 0; ks < 4; ++ks) {
        const int kb = ks * 32 + quad * 8;
#pragma unroll
        for (int ct = 0; ct < 8; ++ct) {
            const int col = ct * 16 + m16;
            frag_ab f;
#pragma unroll
            for (int j = 0; j < 8; ++j)
                f[j] = f2bs(B[(size_t)(kb + j) * CH + col]);
            bfrag[ks][ct] = f;
        }
    }

    const int nstrips = (N_NODES + 63) / 64;
    for (int strip = blockIdx.x; strip < nstrips; strip += gridDim.x) {
        const int row = strip * 64 + wave * 16 + m16;
        const bool valid = row < N_NODES;
        float scale = 1.0f;
        if (cnt != nullptr && valid) {
            int c = cnt[row];
            if (c > 1) scale = 1.0f / (float)c;
        }
        const float4* arow = (const float4*)(A + (size_t)(valid ? row : 0) * CH);
        frag_cd acc[8];
#pragma unroll
        for (int ct = 0; ct < 8; ++ct) acc[ct] = (frag_cd){0.f, 0.f, 0.f, 0.f};
#pragma unroll
        for (int ks = 0; ks < 4; ++ks) {
            float4 a0 = arow[ks * 8 + quad * 2];
            float4 a1 = arow[ks * 8 + quad * 2 + 1];
            frag_ab af;
            af[0] = f2bs(a0.x * scale); af[1] = f2bs(a0.y * scale);
            af[2] = f2bs(a0.z * scale); af[3] = f2bs(a0.w * scale);
            af[4] = f2bs(a1.x * scale); af[5] = f2bs(a1.y * scale);
            af[6] = f2bs(a1.z * scale); af[7] = f2bs(a1.w * scale);
#pragma unroll
            for (int ct = 0; ct < 8; ++ct)
                acc[ct] = __builtin_amdgcn_mfma_f32_16x16x32_bf16(af, bfrag[ks][ct], acc[ct], 0, 0, 0);
        }
        const int obase = strip * 64 + wave * 16 + quad * 4;
#pragma unroll
        for (int ct = 0; ct < 8; ++ct) {
            const int col = ct * 16 + m16;
#pragma unroll
            for (int rg = 0; rg < 4; ++rg) {
                const int r = obase + rg;
                if (r < N_NODES) {
                    const size_t idx = (size_t)r * CH + col;
                    if (accumulate) out[idx] += acc[ct][rg];
                    else out[idx] = acc[ct][rg] + bias[col];
                }
            }
        }
    }
}

__global__ void edge_transform_kernel(const int* __restrict__ ei, const int* __restrict__ et,
                                      const float* __restrict__ x, const float* __restrict__ W,
                                      const int* __restrict__ cnt, float* __restrict__ out) {
    __shared__ float xs[CH];
    const int tid = threadIdx.x;
    for (int e = blockIdx.x; e < N_EDGES; e += gridDim.x) {
        const int src = ei[e];
        const int dst = ei[N_EDGES + e];
        const int r = et[e];
        __syncthreads();
        xs[tid] = x[(size_t)src * CH + tid];
        __syncthreads();
        const int c = cnt[r * N_NODES + dst];
        const float scale = (c > 1) ? (1.0f / (float)c) : 1.0f;
        const float* Wr = W + (size_t)r * CH * CH;
        float acc = 0.f;
#pragma unroll 8
        for (int k = 0; k < CH; ++k) acc += xs[k] * Wr[(size_t)k * CH + tid];
        atomicAdd(&out[(size_t)dst * CH + tid], acc * scale);
    }
}

// ======================= launch =======================

static inline size_t al512(size_t x) { return (x + 511) & ~(size_t)511; }

extern "C" void kernel_launch(void* const* d_in, const int* in_sizes, int n_in,
                              void* d_out, int out_size, void* d_ws, size_t ws_size,
                              hipStream_t stream) {
    const float* x    = (const float*)d_in[0];
    const int*   ei   = (const int*)d_in[1];   // [2, E]: row0=src, row1=dst
    const int*   et   = (const int*)d_in[2];   // [E]
    const float* W    = (const float*)d_in[3]; // [R,128,128]
    const float* root = (const float*)d_in[4]; // [128,128]
    const float* bias = (const float*)d_in[5]; // [128]
    float* out = (float*)d_out;

    // ---- tier-1 workspace layout ----
    size_t o = 0;
    const size_t o_cur  = o; o += al512((size_t)NSUB * NBKT * CUR_PAD * 4);  // 3.2 MB
    const size_t o_bkt  = o; o += al512((size_t)NBKT * BKT_STRIDE * 4);      // 25.6 MB
    const size_t o_perm = o; o += al512((size_t)NBKT * BKT_STRIDE * 4);      // 25.6 MB (spill only)
    const size_t o_bsw  = o; o += al512((size_t)9 * 2048 * 16);
    const size_t o_xb   = o; o += al512((size_t)N_PAD * CH * 2);             // 25.6 MB
    const size_t need_t1 = o;

    const size_t cnt_bytes = (size_t)N_REL * N_NODES * sizeof(int);
    const size_t cnt_rsv   = al512(cnt_bytes);
    const size_t sums51    = (size_t)N_NODES * CH * sizeof(float);

    char* ws = (char*)d_ws;
    if (ws_size >= need_t1) {
        int*      cur    = (int*)(ws + o_cur);
        uint32_t* bucket = (uint32_t*)(ws + o_bkt);
        int*      perm   = (int*)(ws + o_perm);
        short*    Bsw    = (short*)(ws + o_bsw);
        short*    xb     = (short*)(ws + o_xb);

        hipMemsetAsync(cur, 0, (size_t)NSUB * NBKT * CUR_PAD * 4, stream);
        prep_kernel<<<(N_EDGES + 255) / 256, 256, 0, stream>>>(
            ei, et, cur, bucket, x, xb, root, W, Bsw);
        rgcn_mega<<<NBKT, 512, 0, stream>>>(cur, bucket, perm, xb, Bsw, bias, out);
    } else if (ws_size >= cnt_rsv + sums51) {
        int*   cnt  = (int*)d_ws;
        float* sums = (float*)((char*)d_ws + cnt_rsv);
        hipMemsetAsync(cnt, 0, cnt_bytes, stream);
        count_rd_kernel<<<(N_EDGES + 255) / 256, 256, 0, stream>>>(ei, et, cnt);
        gemm_kernel<<<512, 256, 0, stream>>>(x, root, bias, nullptr, out, 0);
        for (int r = 0; r < N_REL; ++r) {
            hipMemsetAsync(sums, 0, sums51, stream);
            scatter_kernel<<<6400, 256, 0, stream>>>(ei, et, x, sums, r);
            gemm_kernel<<<512, 256, 0, stream>>>(sums, W + (size_t)r * CH * CH,
                                                 nullptr, cnt + (size_t)r * N_NODES, out, 1);
        }
    } else {
        int* cnt = (int*)d_ws;
        hipMemsetAsync(cnt, 0, cnt_bytes, stream);
        count_rd_kernel<<<(N_EDGES + 255) / 256, 256, 0, stream>>>(ei, et, cnt);
        gemm_kernel<<<512, 256, 0, stream>>>(x, root, bias, nullptr, out, 0);
        edge_transform_kernel<<<65536, CH, 0, stream>>>(ei, et, x, W, cnt, out);
    }
}